// Round 4
// baseline (524.021 us; speedup 1.0000x reference)
//
#include <hip/hip_runtime.h>

#define EPSF 1e-7f
#define NCLS 46
#define BLOCK 256
#define GRID (23 * 72)      // 1656 blocks; T = 423,936 = 23 * 18,432 threads

__global__ __launch_bounds__(BLOCK) void f1_partial(
    const float* __restrict__ yp,    // y_pred FLOAT32 [N*46]
    const int* __restrict__ yt,      // y_true int32 [N]
    float* __restrict__ g_cs,        // [46] col_sum  (tp+fp)
    float* __restrict__ g_tp,        // [46] tp
    float* __restrict__ g_cnt,       // [46] counts   (tp+fn)
    int n_rows)
{
    __shared__ float s_cs[NCLS], s_tp[NCLS], s_cnt[NCLS];
    const int tid = threadIdx.x;
    for (int i = tid; i < NCLS; i += BLOCK) { s_cs[i] = 0.f; s_tp[i] = 0.f; s_cnt[i] = 0.f; }
    __syncthreads();

    const int T  = BLOCK * GRID;          // multiple of 23
    const int t  = blockIdx.x * BLOCK + tid;
    // A row-pair = 2 rows = 92 floats = 23 float4 slots. Thread owns slot s.
    const int s        = t % 23;
    const int rp0      = t / 23;
    const int rpstride = T / 23;          // 18,432
    const int npairs   = n_rows >> 1;     // 1,000,000

    int cls[4], hi[4];                    // fixed class & row-within-pair per lane-element
    #pragma unroll
    for (int j = 0; j < 4; ++j) {
        int e  = 4 * s + j;               // 0..91 within the pair
        hi[j]  = (e >= 46) ? 1 : 0;       // element lives in second row of pair
        cls[j] = e - 46 * hi[j];
    }

    float cs[4] = {0.f,0.f,0.f,0.f};
    float tp[4] = {0.f,0.f,0.f,0.f};

    for (int rp = rp0; rp < npairs; rp += rpstride) {
        float4 v = *(const float4*)(yp + rp * 92 + 4 * s);   // 16B coalesced
        int2 lab = *(const int2*)(yt + 2 * rp);              // labels of both rows
        float vv[4] = {v.x, v.y, v.z, v.w};
        #pragma unroll
        for (int j = 0; j < 4; ++j) {
            cs[j] += vv[j];
            int labj = hi[j] ? lab.y : lab.x;
            tp[j] += (labj == cls[j]) ? vv[j] : 0.f;
        }
    }

    #pragma unroll
    for (int j = 0; j < 4; ++j) {
        atomicAdd(&s_cs[cls[j]], cs[j]);
        atomicAdd(&s_tp[cls[j]], tp[j]);
    }

    // counts histogram over y_true (8 MB, trivial vs 368 MB)
    for (int i = t; i < n_rows; i += T)
        atomicAdd(&s_cnt[yt[i]], 1.0f);

    // odd-N safety: handle the unpaired last row (not hit for N=2M)
    if ((n_rows & 1) && blockIdx.x == 0 && tid < NCLS) {
        int L = n_rows - 1;
        float v = yp[L * NCLS + tid];
        atomicAdd(&s_cs[tid], v);
        if (yt[L] == tid) atomicAdd(&s_tp[tid], v);
    }

    __syncthreads();
    for (int i = tid; i < NCLS; i += BLOCK) {
        atomicAdd(&g_cs[i],  s_cs[i]);
        atomicAdd(&g_tp[i],  s_tp[i]);
        atomicAdd(&g_cnt[i], s_cnt[i]);
    }
}

__global__ void f1_final(const float* __restrict__ g_cs,
                         const float* __restrict__ g_tp,
                         const float* __restrict__ g_cnt,
                         float* __restrict__ out)     // output float32
{
    const int lane = threadIdx.x;   // single wave of 64
    float f1 = 0.f;
    if (lane < NCLS) {
        float tp = g_tp[lane];
        float p  = tp / (g_cs[lane]  + EPSF);   // tp / (tp+fp+eps)
        float r  = tp / (g_cnt[lane] + EPSF);   // tp / (tp+fn+eps)
        float f  = 2.0f * p * r / (p + r + EPSF);
        f1 = fminf(fmaxf(f, EPSF), 1.0f - EPSF);
    }
    #pragma unroll
    for (int off = 32; off > 0; off >>= 1)
        f1 += __shfl_down(f1, off);
    if (lane == 0)
        out[0] = 1.0f - f1 * (1.0f / 46.0f);
}

extern "C" void kernel_launch(void* const* d_in, const int* in_sizes, int n_in,
                              void* d_out, int out_size, void* d_ws, size_t ws_size,
                              hipStream_t stream)
{
    const float* yp = (const float*)d_in[0];     // f32, N*46
    const int* yt   = (const int*)d_in[1];       // int32, N
    const int n_rows = in_sizes[1];              // N = 2,000,000

    float* g_cs  = (float*)d_ws;
    float* g_tp  = g_cs + NCLS;
    float* g_cnt = g_tp + NCLS;

    hipMemsetAsync(d_ws, 0, 3 * NCLS * sizeof(float), stream);
    f1_partial<<<GRID, BLOCK, 0, stream>>>(yp, yt, g_cs, g_tp, g_cnt, n_rows);
    f1_final<<<1, 64, 0, stream>>>(g_cs, g_tp, g_cnt, (float*)d_out);
}